// Round 4
// baseline (19645.355 us; speedup 1.0000x reference)
//
#include <hip/hip_runtime.h>
#include <hip/hip_bf16.h>
#include <stdint.h>

#define NSTEPS 8192
#define DH 1024
#define DIN 512
#define G5 5120
#define NHOUT ((size_t)NSTEPS * DH)

#define NBLK 128   // scan blocks
#define DPB 8      // dims per block
#define WROWS 40   // 5 gates * DPB
#define THREADS 320

typedef __attribute__((ext_vector_type(8))) __bf16 bf16x8;
typedef __attribute__((ext_vector_type(4))) float f32x4;
typedef __attribute__((ext_vector_type(4))) unsigned int u32x4;
typedef __attribute__((ext_vector_type(2))) unsigned int u32x2;

#if __has_builtin(__builtin_amdgcn_fdot2_f32_bf16)
#define HAVE_DOT2 1
typedef __attribute__((ext_vector_type(2))) short s16x2;
__device__ __forceinline__ s16x2 asp(unsigned int u) {
  union { unsigned int i; s16x2 s; } v;
  v.i = u;
  return v.s;
}
#else
#define HAVE_DOT2 0
#endif

__device__ __forceinline__ float bfbits2f(unsigned int u) {
  union { unsigned int i; float f; } v;
  v.i = u << 16;
  return v.f;
}
__device__ __forceinline__ float bfhi2f(unsigned int u) {
  union { unsigned int i; float f; } v;
  v.i = u & 0xffff0000u;
  return v.f;
}
__device__ __forceinline__ unsigned short f2bfbits(float f) {
  union { __bf16 b; unsigned short u; } v;
  v.b = (__bf16)f;
  return v.u;
}
__device__ __forceinline__ unsigned int pk2(float lo, float hi) {
  return (unsigned int)f2bfbits(lo) | ((unsigned int)f2bfbits(hi) << 16);
}

// ---------------- f32 -> bf16 conversion ----------------
__global__ void cvt_f32_bf16(const float* __restrict__ src,
                             unsigned short* __restrict__ dst, int n4) {
  int i = blockIdx.x * blockDim.x + threadIdx.x;
  int stride = gridDim.x * blockDim.x;
  for (; i < n4; i += stride) {
    float4 v = ((const float4*)src)[i];
    ushort4 o;
    o.x = f2bfbits(v.x);
    o.y = f2bfbits(v.y);
    o.z = f2bfbits(v.z);
    o.w = f2bfbits(v.w);
    ((ushort4*)dst)[i] = o;
  }
}

// ------- GEMM: C[m,n] = sum_k A[m,k]*Bt[n,k] + bias[n], bf16 in/out, f32 acc ----
// permute!=0: n = gate*1024 + j  ->  (j>>3)*40 + gate*8 + (j&7)
#define BM 128
#define BN 128
#define BK 32
#define PSTR 40

__global__ __launch_bounds__(256) void gemm_bt(
    const unsigned short* __restrict__ A,   // [M,K] bf16 bits
    const unsigned short* __restrict__ Bt,  // [N,K] bf16 bits
    const float* __restrict__ bias,         // [N]
    unsigned short* __restrict__ C,         // [M,N] bf16 bits
    int M, int N, int K, int permute) {
  __shared__ unsigned short As[BM * PSTR];
  __shared__ unsigned short Bs[BM * PSTR];
  const int tid = threadIdx.x;
  const int nbn = N / BN;
  const int m0 = (blockIdx.x / nbn) * BM;
  const int n0 = (blockIdx.x % nbn) * BN;
  const int w = tid >> 6;
  const int l = tid & 63;
  const int ln = l & 15;
  const int k8 = l >> 4;
  const int wr = (w >> 1) * 64;
  const int wc = (w & 1) * 64;
  const int row_a = tid >> 2;
  const int c8 = (tid & 3) * 8;

  f32x4 acc[4][4];
#pragma unroll
  for (int a = 0; a < 4; a++)
#pragma unroll
    for (int b = 0; b < 4; b++) acc[a][b] = f32x4{0.f, 0.f, 0.f, 0.f};

  for (int k0 = 0; k0 < K; k0 += BK) {
    uint4 a0 = *(const uint4*)(A + (size_t)(m0 + row_a) * K + k0 + c8);
    uint4 a1 = *(const uint4*)(A + (size_t)(m0 + row_a + 64) * K + k0 + c8);
    uint4 b0 = *(const uint4*)(Bt + (size_t)(n0 + row_a) * K + k0 + c8);
    uint4 b1 = *(const uint4*)(Bt + (size_t)(n0 + row_a + 64) * K + k0 + c8);
    __syncthreads();
    *(uint4*)(As + row_a * PSTR + c8) = a0;
    *(uint4*)(As + (row_a + 64) * PSTR + c8) = a1;
    *(uint4*)(Bs + row_a * PSTR + c8) = b0;
    *(uint4*)(Bs + (row_a + 64) * PSTR + c8) = b1;
    __syncthreads();
    bf16x8 af[4], bfr[4];
#pragma unroll
    for (int mi = 0; mi < 4; mi++)
      af[mi] = *(const bf16x8*)(As + (wr + mi * 16 + ln) * PSTR + k8 * 8);
#pragma unroll
    for (int ni = 0; ni < 4; ni++)
      bfr[ni] = *(const bf16x8*)(Bs + (wc + ni * 16 + ln) * PSTR + k8 * 8);
#pragma unroll
    for (int mi = 0; mi < 4; mi++)
#pragma unroll
      for (int ni = 0; ni < 4; ni++)
        acc[mi][ni] = __builtin_amdgcn_mfma_f32_16x16x32_bf16(
            af[mi], bfr[ni], acc[mi][ni], 0, 0, 0);
  }
#pragma unroll
  for (int ni = 0; ni < 4; ni++) {
    int n = n0 + wc + ni * 16 + ln;
    float bv = bias[n];
#pragma unroll
    for (int mi = 0; mi < 4; mi++) {
#pragma unroll
      for (int r = 0; r < 4; r++) {
        int m = m0 + wr + mi * 16 + k8 * 4 + r;
        size_t ci;
        if (permute) {
          unsigned j = (unsigned)n & 1023u;
          ci = (size_t)m * N +
               (size_t)((j >> 3) * 40u + (((unsigned)n >> 10) << 3) + (j & 7u));
        } else {
          ci = (size_t)m * N + n;
        }
        C[ci] = f2bfbits(acc[mi][ni][r] + bv);
      }
    }
  }
}

// ---------------- persistent scan: 128 blocks, 8 dims each ----------------
// Role-specialized waves:
//   wave 0: poll h(t-1) (conditional quarter re-loads) + stage packed h to LDS
//   wave 2: pipelined gxp prefetch (one-period flight) into LDS ring
//   waves 3,4: replicated gates + state; wave 4 publishes (sc1), wave 3 -> out
//   all waves: matvec rows 8w..8w+7, W held in 64 VGPRs/thread
// Tagged words: (tag=t+1)<<16 | bf16(h). Tags 1..8192 never match zero-fill or
// 0xAAAA poison; stale same-tag words from a prior replay carry identical data
// (deterministic recurrence), so no reset is needed.
__global__ __launch_bounds__(THREADS) void scan_kernel(
    const float* __restrict__ times,
    const float* __restrict__ Ui, const float* __restrict__ Uf2,
    const float* __restrict__ Uo, const float* __restrict__ Uz,
    const float* __restrict__ Ud,
    const unsigned short* __restrict__ gxp,  // [NSTEPS][128][40] bf16 bits
    unsigned int* __restrict__ hbuf,         // [2][DH] tagged words
    float* __restrict__ out) {
  __shared__ unsigned int hpk[DH / 2];      // packed bf16 pairs of h
  __shared__ float s_lds[WROWS];
  __shared__ float gx_ring[2][WROWS];
  __shared__ float t_lds[NSTEPS];           // 32 KB: event times

  const int tid = threadIdx.x;
  const int wid = tid >> 6;
  const int l = tid & 63;
  const int bid = blockIdx.x;
  const int j0 = bid * DPB;
  const int row = tid >> 3;  // 0..39
  const int ln8 = tid & 7;

  // ---- init: W slice into registers (16 x u32x4 = 64 VGPR) ----
  u32x4 Wreg[16];
  {
    const float* Us[5] = {Ui, Uf2, Uo, Uz, Ud};
    const float* wsrc = Us[row >> 3] + (size_t)(j0 + (row & 7)) * DH + ln8 * 8;
#pragma unroll
    for (int i = 0; i < 16; i++) {
      float4 a = *(const float4*)(wsrc + i * 64);
      float4 b = *(const float4*)(wsrc + i * 64 + 4);
      Wreg[i] = u32x4{pk2(a.x, a.y), pk2(a.z, a.w), pk2(b.x, b.y), pk2(b.z, b.w)};
    }
  }
  // times -> LDS
  for (int k = tid; k < NSTEPS / 4; k += THREADS)
    ((float4*)t_lds)[k] = ((const float4*)times)[k];
  // h(=0) staging
  for (int k = tid; k < DH / 2; k += THREADS) hpk[k] = 0u;
  // gx ring slot 0 = gx(0)
  if (wid == 2 && l < WROWS)
    gx_ring[0][l] = bfbits2f((unsigned int)gxp[(size_t)0 * G5 + bid * WROWS + l]);
  float cbv = 0.f, cd_reg = 0.f;  // replicated state (waves 3,4; lanes l<8)
  __syncthreads();

  unsigned short gnext = 0;  // wave2 in-flight gx value (raw bits)

  for (int t = 0; t < NSTEPS; ++t) {
    if (wid == 2 && l < WROWS) {
      // issue load for step t+1 (one full period of flight before use)
      int tn = t + 1 < NSTEPS ? t + 1 : t;
      gnext = gxp[(size_t)tn * G5 + bid * WROWS + l];
    }

    if (wid == 0 && t > 0) {  // wave 0: poll h(t-1)
      const unsigned int want = (unsigned int)t;  // tag = (t-1)+1
      const u32x4* pb = (const u32x4*)(hbuf + ((t - 1) & 1) * DH) + l;
      u32x4 A, B, C2, D2;
      bool ok0 = false, ok1 = false, ok2 = false, ok3 = false;
      for (;;) {
        if (!ok0)
          asm volatile("global_load_dwordx4 %0, %1, off sc1"
                       : "=&v"(A) : "v"(pb) : "memory");
        if (!ok1)
          asm volatile("global_load_dwordx4 %0, %1, off offset:1024 sc1"
                       : "=&v"(B) : "v"(pb) : "memory");
        if (!ok2)
          asm volatile("global_load_dwordx4 %0, %1, off offset:2048 sc1"
                       : "=&v"(C2) : "v"(pb) : "memory");
        if (!ok3)
          asm volatile("global_load_dwordx4 %0, %1, off offset:3072 sc1"
                       : "=&v"(D2) : "v"(pb) : "memory");
        asm volatile("s_waitcnt vmcnt(0)" ::: "memory");
        ok0 = (A[0] >> 16) == want && (A[1] >> 16) == want &&
              (A[2] >> 16) == want && (A[3] >> 16) == want;
        ok1 = (B[0] >> 16) == want && (B[1] >> 16) == want &&
              (B[2] >> 16) == want && (B[3] >> 16) == want;
        ok2 = (C2[0] >> 16) == want && (C2[1] >> 16) == want &&
              (C2[2] >> 16) == want && (C2[3] >> 16) == want;
        ok3 = (D2[0] >> 16) == want && (D2[1] >> 16) == want &&
              (D2[2] >> 16) == want && (D2[3] >> 16) == want;
        if (__all(ok0 && ok1 && ok2 && ok3)) break;
      }
      // stage packed h
      *(u32x2*)(hpk + 2 * l) =
          u32x2{(A[0] & 0xffffu) | (A[1] << 16), (A[2] & 0xffffu) | (A[3] << 16)};
      *(u32x2*)(hpk + 128 + 2 * l) =
          u32x2{(B[0] & 0xffffu) | (B[1] << 16), (B[2] & 0xffffu) | (B[3] << 16)};
      *(u32x2*)(hpk + 256 + 2 * l) = u32x2{(C2[0] & 0xffffu) | (C2[1] << 16),
                                           (C2[2] & 0xffffu) | (C2[3] << 16)};
      *(u32x2*)(hpk + 384 + 2 * l) = u32x2{(D2[0] & 0xffffu) | (D2[1] << 16),
                                           (D2[2] & 0xffffu) | (D2[3] << 16)};
    }
    __syncthreads();  // b1: h staged

    // ---- matvec: 40 rows x 1024, 8 lanes/row, W in regs ----
    {
#if HAVE_DOT2
      float a0 = 0.f, a1 = 0.f, a2 = 0.f, a3 = 0.f;
#pragma unroll
      for (int i = 0; i < 16; i++) {
        u32x4 hv = *(const u32x4*)(hpk + i * 32 + ln8 * 4);
        a0 = __builtin_amdgcn_fdot2_f32_bf16(asp(Wreg[i][0]), asp(hv[0]), a0, false);
        a1 = __builtin_amdgcn_fdot2_f32_bf16(asp(Wreg[i][1]), asp(hv[1]), a1, false);
        a2 = __builtin_amdgcn_fdot2_f32_bf16(asp(Wreg[i][2]), asp(hv[2]), a2, false);
        a3 = __builtin_amdgcn_fdot2_f32_bf16(asp(Wreg[i][3]), asp(hv[3]), a3, false);
      }
      float s = (a0 + a1) + (a2 + a3);
#else
      float a0 = 0.f, a1 = 0.f;
#pragma unroll
      for (int i = 0; i < 16; i++) {
        u32x4 hv = *(const u32x4*)(hpk + i * 32 + ln8 * 4);
        a0 += bfbits2f(Wreg[i][0] & 0xffffu) * bfbits2f(hv[0] & 0xffffu);
        a1 += bfhi2f(Wreg[i][0]) * bfhi2f(hv[0]);
        a0 += bfbits2f(Wreg[i][1] & 0xffffu) * bfbits2f(hv[1] & 0xffffu);
        a1 += bfhi2f(Wreg[i][1]) * bfhi2f(hv[1]);
        a0 += bfbits2f(Wreg[i][2] & 0xffffu) * bfbits2f(hv[2] & 0xffffu);
        a1 += bfhi2f(Wreg[i][2]) * bfhi2f(hv[2]);
        a0 += bfbits2f(Wreg[i][3] & 0xffffu) * bfbits2f(hv[3] & 0xffffu);
        a1 += bfhi2f(Wreg[i][3]) * bfhi2f(hv[3]);
      }
      float s = a0 + a1;
#endif
      s += __shfl_xor(s, 1);
      s += __shfl_xor(s, 2);
      s += __shfl_xor(s, 4);
      if (ln8 == 0) s_lds[row] = s;
    }
    if (wid == 2 && l < WROWS)  // write gx(t+1) into ring (load long arrived)
      gx_ring[(t + 1) & 1][l] = bfbits2f((unsigned int)gnext);
    __syncthreads();  // b2: s_lds + ring ready

    if (wid >= 3) {  // waves 3,4: replicated gates + state
      unsigned int word = 0;
      float h = 0.f, cn = 0.f, adv = 0.f, ig = 0.f, fg = 0.f, z = 0.f,
            og = 0.f;
      if (l < DPB) {
        const float* gx = gx_ring[t & 1];
        float si = s_lds[l] + gx[l];
        float sf = s_lds[8 + l] + gx[8 + l];
        float so = s_lds[16 + l] + gx[16 + l];
        float sz = s_lds[24 + l] + gx[24 + l];
        float sd = s_lds[32 + l] + gx[32 + l];
        ig = 1.f / (1.f + __expf(-si));
        fg = 1.f / (1.f + __expf(-sf));
        og = 1.f / (1.f + __expf(-so));
        z = 1.f - 2.f / (__expf(2.f * sz) + 1.f);
        cn = fg * cd_reg + ig * z;
        float th = 1.f - 2.f / (__expf(2.f * cn) + 1.f);
        h = og * th;
        adv = sd;
        word = (((unsigned int)(t + 1) & 0xffffu) << 16) |
               (unsigned int)f2bfbits(h);
      }
      if (wid == 4) {  // publish ASAP
        u32x4 pubv = {__shfl(word, 4 * l + 0), __shfl(word, 4 * l + 1),
                      __shfl(word, 4 * l + 2), __shfl(word, 4 * l + 3)};
        if (l < 2) {
          u32x4* dst = (u32x4*)(hbuf + (t & 1) * DH + bid * DPB) + l;
          asm volatile("global_store_dwordx4 %0, %1, off sc1" ::"v"(dst),
                       "v"(pubv)
                       : "memory");
        }
      }
      if (l < DPB) {
        float dec = fmaxf(adv, 0.f) + __logf(1.f + __expf(-fabsf(adv)));
        cbv = fg * cbv + ig * z;
        float dtn = t_lds[t + (t < NSTEPS - 1 ? 1 : 0)] - t_lds[t];
        cd_reg = cbv + (cn - cbv) * __expf(-dec * dtn);
        if (wid == 3) {
          int j = j0 + l;
          out[(size_t)t * DH + j] = h;
          out[NHOUT + (size_t)t * DH + j] = cn;
          out[2 * NHOUT + (size_t)t * DH + j] = dec;
        }
      }
    }
    // waves 0..2 run ahead to the next iteration; wave 0 starts polling h(t).
  }
  if (wid == 3 && l < DPB) out[3 * NHOUT + j0 + l] = cbv;
}

extern "C" void kernel_launch(void* const* d_in, const int* in_sizes, int n_in,
                              void* d_out, int out_size, void* d_ws,
                              size_t ws_size, hipStream_t stream) {
  (void)in_sizes; (void)n_in; (void)out_size; (void)ws_size;
  const float* times = (const float*)d_in[0];
  const float* marks = (const float*)d_in[1];
  const float* Wp = (const float*)d_in[3];
  const float* bp = (const float*)d_in[4];
  const float* Wi = (const float*)d_in[5];
  const float* bi = (const float*)d_in[6];
  const float* Wf = (const float*)d_in[7];
  const float* bf_ = (const float*)d_in[8];
  const float* Wo = (const float*)d_in[9];
  const float* bo = (const float*)d_in[10];
  const float* Wz = (const float*)d_in[11];
  const float* bz = (const float*)d_in[12];
  const float* Wd = (const float*)d_in[13];
  const float* bd = (const float*)d_in[14];
  const float* Ui = (const float*)d_in[15];
  const float* Uf2 = (const float*)d_in[16];
  const float* Uo = (const float*)d_in[17];
  const float* Uz = (const float*)d_in[18];
  const float* Ud = (const float*)d_in[19];

  char* ws = (char*)d_ws;
  size_t off = 0;
  auto alloc = [&](size_t bytes) -> void* {
    void* p = ws + off;
    off += (bytes + 255) & ~(size_t)255;
    return p;
  };
  unsigned short* marks_bf = (unsigned short*)alloc((size_t)NSTEPS * DIN * 2);
  unsigned short* X_bf = (unsigned short*)alloc((size_t)NSTEPS * DH * 2);
  unsigned short* Wp_bf = (unsigned short*)alloc((size_t)DH * DIN * 2);
  unsigned short* W5_bf = (unsigned short*)alloc((size_t)G5 * DH * 2);
  float* bcat = (float*)alloc((size_t)G5 * 4);
  unsigned short* gxp = (unsigned short*)alloc((size_t)NSTEPS * G5 * 2);
  unsigned int* hbuf = (unsigned int*)alloc((size_t)2 * DH * 4);

  auto cvt = [&](const float* s, unsigned short* d, int n) {
    int n4 = n / 4;
    int grid = (n4 + 255) / 256;
    if (grid > 2048) grid = 2048;
    cvt_f32_bf16<<<grid, 256, 0, stream>>>(s, d, n4);
  };
  cvt(marks, marks_bf, NSTEPS * DIN);
  cvt(Wp, Wp_bf, DH * DIN);
  cvt(Wi, W5_bf + (size_t)0 * DH * DH, DH * DH);
  cvt(Wf, W5_bf + (size_t)1 * DH * DH, DH * DH);
  cvt(Wo, W5_bf + (size_t)2 * DH * DH, DH * DH);
  cvt(Wz, W5_bf + (size_t)3 * DH * DH, DH * DH);
  cvt(Wd, W5_bf + (size_t)4 * DH * DH, DH * DH);
  hipMemcpyAsync(bcat + 0 * DH, bi, DH * sizeof(float),
                 hipMemcpyDeviceToDevice, stream);
  hipMemcpyAsync(bcat + 1 * DH, bf_, DH * sizeof(float),
                 hipMemcpyDeviceToDevice, stream);
  hipMemcpyAsync(bcat + 2 * DH, bo, DH * sizeof(float),
                 hipMemcpyDeviceToDevice, stream);
  hipMemcpyAsync(bcat + 3 * DH, bz, DH * sizeof(float),
                 hipMemcpyDeviceToDevice, stream);
  hipMemcpyAsync(bcat + 4 * DH, bd, DH * sizeof(float),
                 hipMemcpyDeviceToDevice, stream);

  // X = marks @ Wp.T + bp   [8192,1024]
  gemm_bt<<<(NSTEPS / BM) * (DH / BN), 256, 0, stream>>>(
      marks_bf, Wp_bf, bp, X_bf, NSTEPS, DH, DIN, 0);
  // gxp = permute(X @ [Wi;Wf;Wo;Wz;Wd].T + bcat)   [8192][128][5][8]
  gemm_bt<<<(NSTEPS / BM) * (G5 / BN), 256, 0, stream>>>(
      X_bf, W5_bf, bcat, gxp, NSTEPS, G5, DH, 1);

  scan_kernel<<<NBLK, THREADS, 0, stream>>>(times, Ui, Uf2, Uo, Uz, Ud, gxp,
                                            hbuf, (float*)d_out);
}

// Round 5
// 18340.967 us; speedup vs baseline: 1.0711x; 1.0711x over previous
//
#include <hip/hip_runtime.h>
#include <hip/hip_bf16.h>
#include <stdint.h>

#define NSTEPS 8192
#define DH 1024
#define DIN 512
#define G5 5120
#define NHOUT ((size_t)NSTEPS * DH)

#define NBLK 128   // scan blocks
#define DPB 8      // dims per block
#define WROWS 40   // 5 gates * DPB
#define THREADS 320

typedef __attribute__((ext_vector_type(8))) __bf16 bf16x8;
typedef __attribute__((ext_vector_type(4))) float f32x4;
typedef __attribute__((ext_vector_type(4))) unsigned int u32x4;
typedef __attribute__((ext_vector_type(2))) unsigned int u32x2;

#if __has_builtin(__builtin_amdgcn_fdot2_f32_bf16)
#define HAVE_DOT2 1
typedef __attribute__((ext_vector_type(2))) short s16x2;
__device__ __forceinline__ s16x2 asp(unsigned int u) {
  union { unsigned int i; s16x2 s; } v;
  v.i = u;
  return v.s;
}
#else
#define HAVE_DOT2 0
#endif

__device__ __forceinline__ float bfbits2f(unsigned int u) {
  union { unsigned int i; float f; } v;
  v.i = u << 16;
  return v.f;
}
__device__ __forceinline__ float bfhi2f(unsigned int u) {
  union { unsigned int i; float f; } v;
  v.i = u & 0xffff0000u;
  return v.f;
}
__device__ __forceinline__ unsigned short f2bfbits(float f) {
  union { __bf16 b; unsigned short u; } v;
  v.b = (__bf16)f;
  return v.u;
}
__device__ __forceinline__ unsigned int pk2(float lo, float hi) {
  return (unsigned int)f2bfbits(lo) | ((unsigned int)f2bfbits(hi) << 16);
}

// ---------------- f32 -> bf16 conversion ----------------
__global__ void cvt_f32_bf16(const float* __restrict__ src,
                             unsigned short* __restrict__ dst, int n4) {
  int i = blockIdx.x * blockDim.x + threadIdx.x;
  int stride = gridDim.x * blockDim.x;
  for (; i < n4; i += stride) {
    float4 v = ((const float4*)src)[i];
    ushort4 o;
    o.x = f2bfbits(v.x);
    o.y = f2bfbits(v.y);
    o.z = f2bfbits(v.z);
    o.w = f2bfbits(v.w);
    ((ushort4*)dst)[i] = o;
  }
}

// ------- GEMM: C[m,n] = sum_k A[m,k]*Bt[n,k] + bias[n], bf16 in/out, f32 acc ----
// permute!=0: n = gate*1024 + j  ->  (j>>3)*40 + gate*8 + (j&7)
#define BM 128
#define BN 128
#define BK 32
#define PSTR 40

__global__ __launch_bounds__(256) void gemm_bt(
    const unsigned short* __restrict__ A,   // [M,K] bf16 bits
    const unsigned short* __restrict__ Bt,  // [N,K] bf16 bits
    const float* __restrict__ bias,         // [N]
    unsigned short* __restrict__ C,         // [M,N] bf16 bits
    int M, int N, int K, int permute) {
  __shared__ unsigned short As[BM * PSTR];
  __shared__ unsigned short Bs[BM * PSTR];
  const int tid = threadIdx.x;
  const int nbn = N / BN;
  const int m0 = (blockIdx.x / nbn) * BM;
  const int n0 = (blockIdx.x % nbn) * BN;
  const int w = tid >> 6;
  const int l = tid & 63;
  const int ln = l & 15;
  const int k8 = l >> 4;
  const int wr = (w >> 1) * 64;
  const int wc = (w & 1) * 64;
  const int row_a = tid >> 2;
  const int c8 = (tid & 3) * 8;

  f32x4 acc[4][4];
#pragma unroll
  for (int a = 0; a < 4; a++)
#pragma unroll
    for (int b = 0; b < 4; b++) acc[a][b] = f32x4{0.f, 0.f, 0.f, 0.f};

  for (int k0 = 0; k0 < K; k0 += BK) {
    uint4 a0 = *(const uint4*)(A + (size_t)(m0 + row_a) * K + k0 + c8);
    uint4 a1 = *(const uint4*)(A + (size_t)(m0 + row_a + 64) * K + k0 + c8);
    uint4 b0 = *(const uint4*)(Bt + (size_t)(n0 + row_a) * K + k0 + c8);
    uint4 b1 = *(const uint4*)(Bt + (size_t)(n0 + row_a + 64) * K + k0 + c8);
    __syncthreads();
    *(uint4*)(As + row_a * PSTR + c8) = a0;
    *(uint4*)(As + (row_a + 64) * PSTR + c8) = a1;
    *(uint4*)(Bs + row_a * PSTR + c8) = b0;
    *(uint4*)(Bs + (row_a + 64) * PSTR + c8) = b1;
    __syncthreads();
    bf16x8 af[4], bfr[4];
#pragma unroll
    for (int mi = 0; mi < 4; mi++)
      af[mi] = *(const bf16x8*)(As + (wr + mi * 16 + ln) * PSTR + k8 * 8);
#pragma unroll
    for (int ni = 0; ni < 4; ni++)
      bfr[ni] = *(const bf16x8*)(Bs + (wc + ni * 16 + ln) * PSTR + k8 * 8);
#pragma unroll
    for (int mi = 0; mi < 4; mi++)
#pragma unroll
      for (int ni = 0; ni < 4; ni++)
        acc[mi][ni] = __builtin_amdgcn_mfma_f32_16x16x32_bf16(
            af[mi], bfr[ni], acc[mi][ni], 0, 0, 0);
  }
#pragma unroll
  for (int ni = 0; ni < 4; ni++) {
    int n = n0 + wc + ni * 16 + ln;
    float bv = bias[n];
#pragma unroll
    for (int mi = 0; mi < 4; mi++) {
#pragma unroll
      for (int r = 0; r < 4; r++) {
        int m = m0 + wr + mi * 16 + k8 * 4 + r;
        size_t ci;
        if (permute) {
          unsigned j = (unsigned)n & 1023u;
          ci = (size_t)m * N +
               (size_t)((j >> 3) * 40u + (((unsigned)n >> 10) << 3) + (j & 7u));
        } else {
          ci = (size_t)m * N + n;
        }
        C[ci] = f2bfbits(acc[mi][ni][r] + bv);
      }
    }
  }
}

// ---------------- persistent scan: 128 blocks, 8 dims each ----------------
// Role-specialized waves:
//   wave 0: poll h(t-1) (unconditional 4-line sweep) + stage packed h to LDS
//   wave 2: pipelined gxp prefetch (one-period flight) into LDS ring
//   waves 3,4: replicated gates + state; wave 4 publishes (sc1), wave 3 -> out
//   all waves: matvec rows 8w..8w+7, W held in 64 VGPRs/thread
// __launch_bounds__(THREADS, 1): min 1 wave/EU -> full VGPR budget so Wreg
// stays in registers (r4's default budget spilled it to scratch: VGPR=76).
// Tagged words: (tag=t+1)<<16 | bf16(h). Tags 1..8192 never match zero-fill or
// 0xAAAA poison; stale same-tag words from a prior replay carry identical data
// (deterministic recurrence), so no reset is needed.
__global__ __launch_bounds__(THREADS, 1) void scan_kernel(
    const float* __restrict__ times,
    const float* __restrict__ Ui, const float* __restrict__ Uf2,
    const float* __restrict__ Uo, const float* __restrict__ Uz,
    const float* __restrict__ Ud,
    const unsigned short* __restrict__ gxp,  // [NSTEPS][128][40] bf16 bits
    unsigned int* __restrict__ hbuf,         // [2][DH] tagged words
    float* __restrict__ out) {
  __shared__ unsigned int hpk[DH / 2];      // packed bf16 pairs of h
  __shared__ float s_lds[WROWS];
  __shared__ float gx_ring[2][WROWS];
  __shared__ float t_lds[NSTEPS];           // 32 KB: event times

  const int tid = threadIdx.x;
  const int wid = tid >> 6;
  const int l = tid & 63;
  const int bid = blockIdx.x;
  const int j0 = bid * DPB;
  const int row = tid >> 3;  // 0..39
  const int ln8 = tid & 7;

  // ---- init: W slice into registers (16 x u32x4 = 64 VGPR) ----
  u32x4 Wreg[16];
  {
    const float* Us[5] = {Ui, Uf2, Uo, Uz, Ud};
    const float* wsrc = Us[row >> 3] + (size_t)(j0 + (row & 7)) * DH + ln8 * 8;
#pragma unroll
    for (int i = 0; i < 16; i++) {
      float4 a = *(const float4*)(wsrc + i * 64);
      float4 b = *(const float4*)(wsrc + i * 64 + 4);
      Wreg[i] = u32x4{pk2(a.x, a.y), pk2(a.z, a.w), pk2(b.x, b.y), pk2(b.z, b.w)};
    }
  }
  // times -> LDS
  for (int k = tid; k < NSTEPS / 4; k += THREADS)
    ((float4*)t_lds)[k] = ((const float4*)times)[k];
  // h(=0) staging
  for (int k = tid; k < DH / 2; k += THREADS) hpk[k] = 0u;
  // gx ring slot 0 = gx(0)
  if (wid == 2 && l < WROWS)
    gx_ring[0][l] = bfbits2f((unsigned int)gxp[(size_t)0 * G5 + bid * WROWS + l]);
  float cbv = 0.f, cd_reg = 0.f;  // replicated state (waves 3,4; lanes l<8)
  __syncthreads();

  unsigned short gnext = 0;  // wave2 in-flight gx value (raw bits)

  for (int t = 0; t < NSTEPS; ++t) {
    if (wid == 2 && l < WROWS) {
      // issue load for step t+1 (one full period of flight before use)
      int tn = t + 1 < NSTEPS ? t + 1 : t;
      gnext = gxp[(size_t)tn * G5 + bid * WROWS + l];
    }

    if (wid == 0 && t > 0) {  // wave 0: poll h(t-1)
      const unsigned int want = (unsigned int)t;  // tag = (t-1)+1
      const u32x4* pb = (const u32x4*)(hbuf + ((t - 1) & 1) * DH) + l;
      u32x4 A, B, C2, D2;
      for (;;) {
        asm volatile(
            "global_load_dwordx4 %0, %4, off sc1\n\t"
            "global_load_dwordx4 %1, %4, off offset:1024 sc1\n\t"
            "global_load_dwordx4 %2, %4, off offset:2048 sc1\n\t"
            "global_load_dwordx4 %3, %4, off offset:3072 sc1\n\t"
            "s_waitcnt vmcnt(0)"
            : "=&v"(A), "=&v"(B), "=&v"(C2), "=&v"(D2)
            : "v"(pb)
            : "memory");
        bool ok = (A[0] >> 16) == want && (A[1] >> 16) == want &&
                  (A[2] >> 16) == want && (A[3] >> 16) == want &&
                  (B[0] >> 16) == want && (B[1] >> 16) == want &&
                  (B[2] >> 16) == want && (B[3] >> 16) == want &&
                  (C2[0] >> 16) == want && (C2[1] >> 16) == want &&
                  (C2[2] >> 16) == want && (C2[3] >> 16) == want &&
                  (D2[0] >> 16) == want && (D2[1] >> 16) == want &&
                  (D2[2] >> 16) == want && (D2[3] >> 16) == want;
        if (__all(ok)) break;
      }
      // stage packed h
      *(u32x2*)(hpk + 2 * l) =
          u32x2{(A[0] & 0xffffu) | (A[1] << 16), (A[2] & 0xffffu) | (A[3] << 16)};
      *(u32x2*)(hpk + 128 + 2 * l) =
          u32x2{(B[0] & 0xffffu) | (B[1] << 16), (B[2] & 0xffffu) | (B[3] << 16)};
      *(u32x2*)(hpk + 256 + 2 * l) = u32x2{(C2[0] & 0xffffu) | (C2[1] << 16),
                                           (C2[2] & 0xffffu) | (C2[3] << 16)};
      *(u32x2*)(hpk + 384 + 2 * l) = u32x2{(D2[0] & 0xffffu) | (D2[1] << 16),
                                           (D2[2] & 0xffffu) | (D2[3] << 16)};
    }
    __syncthreads();  // b1: h staged

    // ---- matvec: 40 rows x 1024, 8 lanes/row, W in regs ----
    {
#if HAVE_DOT2
      float a0 = 0.f, a1 = 0.f, a2 = 0.f, a3 = 0.f;
#pragma unroll
      for (int i = 0; i < 16; i++) {
        u32x4 hv = *(const u32x4*)(hpk + i * 32 + ln8 * 4);
        a0 = __builtin_amdgcn_fdot2_f32_bf16(asp(Wreg[i][0]), asp(hv[0]), a0, false);
        a1 = __builtin_amdgcn_fdot2_f32_bf16(asp(Wreg[i][1]), asp(hv[1]), a1, false);
        a2 = __builtin_amdgcn_fdot2_f32_bf16(asp(Wreg[i][2]), asp(hv[2]), a2, false);
        a3 = __builtin_amdgcn_fdot2_f32_bf16(asp(Wreg[i][3]), asp(hv[3]), a3, false);
      }
      float s = (a0 + a1) + (a2 + a3);
#else
      float a0 = 0.f, a1 = 0.f;
#pragma unroll
      for (int i = 0; i < 16; i++) {
        u32x4 hv = *(const u32x4*)(hpk + i * 32 + ln8 * 4);
        a0 += bfbits2f(Wreg[i][0] & 0xffffu) * bfbits2f(hv[0] & 0xffffu);
        a1 += bfhi2f(Wreg[i][0]) * bfhi2f(hv[0]);
        a0 += bfbits2f(Wreg[i][1] & 0xffffu) * bfbits2f(hv[1] & 0xffffu);
        a1 += bfhi2f(Wreg[i][1]) * bfhi2f(hv[1]);
        a0 += bfbits2f(Wreg[i][2] & 0xffffu) * bfbits2f(hv[2] & 0xffffu);
        a1 += bfhi2f(Wreg[i][2]) * bfhi2f(hv[2]);
        a0 += bfbits2f(Wreg[i][3] & 0xffffu) * bfbits2f(hv[3] & 0xffffu);
        a1 += bfhi2f(Wreg[i][3]) * bfhi2f(hv[3]);
      }
      float s = a0 + a1;
#endif
      s += __shfl_xor(s, 1);
      s += __shfl_xor(s, 2);
      s += __shfl_xor(s, 4);
      if (ln8 == 0) s_lds[row] = s;
    }
    if (wid == 2 && l < WROWS)  // write gx(t+1) into ring (load long arrived)
      gx_ring[(t + 1) & 1][l] = bfbits2f((unsigned int)gnext);
    __syncthreads();  // b2: s_lds + ring ready

    if (wid >= 3) {  // waves 3,4: replicated gates + state
      unsigned int word = 0;
      float h = 0.f, cn = 0.f, adv = 0.f, ig = 0.f, fg = 0.f, z = 0.f,
            og = 0.f;
      if (l < DPB) {
        const float* gx = gx_ring[t & 1];
        float si = s_lds[l] + gx[l];
        float sf = s_lds[8 + l] + gx[8 + l];
        float so = s_lds[16 + l] + gx[16 + l];
        float sz = s_lds[24 + l] + gx[24 + l];
        float sd = s_lds[32 + l] + gx[32 + l];
        ig = 1.f / (1.f + __expf(-si));
        fg = 1.f / (1.f + __expf(-sf));
        og = 1.f / (1.f + __expf(-so));
        z = 1.f - 2.f / (__expf(2.f * sz) + 1.f);
        cn = fg * cd_reg + ig * z;
        float th = 1.f - 2.f / (__expf(2.f * cn) + 1.f);
        h = og * th;
        adv = sd;
        word = (((unsigned int)(t + 1) & 0xffffu) << 16) |
               (unsigned int)f2bfbits(h);
      }
      if (wid == 4) {  // publish ASAP
        u32x4 pubv = {__shfl(word, 4 * l + 0), __shfl(word, 4 * l + 1),
                      __shfl(word, 4 * l + 2), __shfl(word, 4 * l + 3)};
        if (l < 2) {
          u32x4* dst = (u32x4*)(hbuf + (t & 1) * DH + bid * DPB) + l;
          asm volatile("global_store_dwordx4 %0, %1, off sc1" ::"v"(dst),
                       "v"(pubv)
                       : "memory");
        }
      }
      if (l < DPB) {
        float dec = fmaxf(adv, 0.f) + __logf(1.f + __expf(-fabsf(adv)));
        cbv = fg * cbv + ig * z;
        float dtn = t_lds[t + (t < NSTEPS - 1 ? 1 : 0)] - t_lds[t];
        cd_reg = cbv + (cn - cbv) * __expf(-dec * dtn);
        if (wid == 3) {
          int j = j0 + l;
          out[(size_t)t * DH + j] = h;
          out[NHOUT + (size_t)t * DH + j] = cn;
          out[2 * NHOUT + (size_t)t * DH + j] = dec;
        }
      }
    }
    // waves 0..2 run ahead to the next iteration; wave 0 starts polling h(t).
  }
  if (wid == 3 && l < DPB) out[3 * NHOUT + j0 + l] = cbv;
}

extern "C" void kernel_launch(void* const* d_in, const int* in_sizes, int n_in,
                              void* d_out, int out_size, void* d_ws,
                              size_t ws_size, hipStream_t stream) {
  (void)in_sizes; (void)n_in; (void)out_size; (void)ws_size;
  const float* times = (const float*)d_in[0];
  const float* marks = (const float*)d_in[1];
  const float* Wp = (const float*)d_in[3];
  const float* bp = (const float*)d_in[4];
  const float* Wi = (const float*)d_in[5];
  const float* bi = (const float*)d_in[6];
  const float* Wf = (const float*)d_in[7];
  const float* bf_ = (const float*)d_in[8];
  const float* Wo = (const float*)d_in[9];
  const float* bo = (const float*)d_in[10];
  const float* Wz = (const float*)d_in[11];
  const float* bz = (const float*)d_in[12];
  const float* Wd = (const float*)d_in[13];
  const float* bd = (const float*)d_in[14];
  const float* Ui = (const float*)d_in[15];
  const float* Uf2 = (const float*)d_in[16];
  const float* Uo = (const float*)d_in[17];
  const float* Uz = (const float*)d_in[18];
  const float* Ud = (const float*)d_in[19];

  char* ws = (char*)d_ws;
  size_t off = 0;
  auto alloc = [&](size_t bytes) -> void* {
    void* p = ws + off;
    off += (bytes + 255) & ~(size_t)255;
    return p;
  };
  unsigned short* marks_bf = (unsigned short*)alloc((size_t)NSTEPS * DIN * 2);
  unsigned short* X_bf = (unsigned short*)alloc((size_t)NSTEPS * DH * 2);
  unsigned short* Wp_bf = (unsigned short*)alloc((size_t)DH * DIN * 2);
  unsigned short* W5_bf = (unsigned short*)alloc((size_t)G5 * DH * 2);
  float* bcat = (float*)alloc((size_t)G5 * 4);
  unsigned short* gxp = (unsigned short*)alloc((size_t)NSTEPS * G5 * 2);
  unsigned int* hbuf = (unsigned int*)alloc((size_t)2 * DH * 4);

  auto cvt = [&](const float* s, unsigned short* d, int n) {
    int n4 = n / 4;
    int grid = (n4 + 255) / 256;
    if (grid > 2048) grid = 2048;
    cvt_f32_bf16<<<grid, 256, 0, stream>>>(s, d, n4);
  };
  cvt(marks, marks_bf, NSTEPS * DIN);
  cvt(Wp, Wp_bf, DH * DIN);
  cvt(Wi, W5_bf + (size_t)0 * DH * DH, DH * DH);
  cvt(Wf, W5_bf + (size_t)1 * DH * DH, DH * DH);
  cvt(Wo, W5_bf + (size_t)2 * DH * DH, DH * DH);
  cvt(Wz, W5_bf + (size_t)3 * DH * DH, DH * DH);
  cvt(Wd, W5_bf + (size_t)4 * DH * DH, DH * DH);
  hipMemcpyAsync(bcat + 0 * DH, bi, DH * sizeof(float),
                 hipMemcpyDeviceToDevice, stream);
  hipMemcpyAsync(bcat + 1 * DH, bf_, DH * sizeof(float),
                 hipMemcpyDeviceToDevice, stream);
  hipMemcpyAsync(bcat + 2 * DH, bo, DH * sizeof(float),
                 hipMemcpyDeviceToDevice, stream);
  hipMemcpyAsync(bcat + 3 * DH, bz, DH * sizeof(float),
                 hipMemcpyDeviceToDevice, stream);
  hipMemcpyAsync(bcat + 4 * DH, bd, DH * sizeof(float),
                 hipMemcpyDeviceToDevice, stream);

  // X = marks @ Wp.T + bp   [8192,1024]
  gemm_bt<<<(NSTEPS / BM) * (DH / BN), 256, 0, stream>>>(
      marks_bf, Wp_bf, bp, X_bf, NSTEPS, DH, DIN, 0);
  // gxp = permute(X @ [Wi;Wf;Wo;Wz;Wd].T + bcat)   [8192][128][5][8]
  gemm_bt<<<(NSTEPS / BM) * (G5 / BN), 256, 0, stream>>>(
      X_bf, W5_bf, bcat, gxp, NSTEPS, G5, DH, 1);

  scan_kernel<<<NBLK, THREADS, 0, stream>>>(times, Ui, Uf2, Uo, Uz, Ud, gxp,
                                            hbuf, (float*)d_out);
}

// Round 6
// 18332.031 us; speedup vs baseline: 1.0716x; 1.0005x over previous
//
#include <hip/hip_runtime.h>
#include <hip/hip_bf16.h>
#include <stdint.h>

#define NSTEPS 8192
#define DH 1024
#define DIN 512
#define G5 5120
#define NHOUT ((size_t)NSTEPS * DH)

#define NBLK 64    // scan blocks
#define DPB 16     // dims per block
#define WROWS 80   // 5 gates * DPB
#define THREADS 640

typedef __attribute__((ext_vector_type(8))) __bf16 bf16x8;
typedef __attribute__((ext_vector_type(4))) float f32x4;
typedef __attribute__((ext_vector_type(4))) unsigned int u32x4;
typedef __attribute__((ext_vector_type(2))) unsigned int u32x2;

#if __has_builtin(__builtin_amdgcn_fdot2_f32_bf16)
#define HAVE_DOT2 1
typedef __attribute__((ext_vector_type(2))) short s16x2;
__device__ __forceinline__ s16x2 asp(unsigned int u) {
  union { unsigned int i; s16x2 s; } v;
  v.i = u;
  return v.s;
}
#else
#define HAVE_DOT2 0
#endif

__device__ __forceinline__ float bfbits2f(unsigned int u) {
  union { unsigned int i; float f; } v;
  v.i = u << 16;
  return v.f;
}
__device__ __forceinline__ float bfhi2f(unsigned int u) {
  union { unsigned int i; float f; } v;
  v.i = u & 0xffff0000u;
  return v.f;
}
__device__ __forceinline__ unsigned short f2bfbits(float f) {
  union { __bf16 b; unsigned short u; } v;
  v.b = (__bf16)f;
  return v.u;
}
__device__ __forceinline__ unsigned int pk2(float lo, float hi) {
  return (unsigned int)f2bfbits(lo) | ((unsigned int)f2bfbits(hi) << 16);
}

// ---------------- f32 -> bf16 conversion ----------------
__global__ void cvt_f32_bf16(const float* __restrict__ src,
                             unsigned short* __restrict__ dst, int n4) {
  int i = blockIdx.x * blockDim.x + threadIdx.x;
  int stride = gridDim.x * blockDim.x;
  for (; i < n4; i += stride) {
    float4 v = ((const float4*)src)[i];
    ushort4 o;
    o.x = f2bfbits(v.x);
    o.y = f2bfbits(v.y);
    o.z = f2bfbits(v.z);
    o.w = f2bfbits(v.w);
    ((ushort4*)dst)[i] = o;
  }
}

// ------- GEMM: C[m,n] = sum_k A[m,k]*Bt[n,k] + bias[n], bf16 in/out, f32 acc ----
// permute!=0: n = gate*1024 + j  ->  (j>>4)*80 + gate*16 + (j&15)
// i.e. layout [m][block(64)][gate(5)][dim(16)] for the scan's contiguous reads.
#define BM 128
#define BN 128
#define BK 32
#define PSTR 40

__global__ __launch_bounds__(256) void gemm_bt(
    const unsigned short* __restrict__ A,   // [M,K] bf16 bits
    const unsigned short* __restrict__ Bt,  // [N,K] bf16 bits
    const float* __restrict__ bias,         // [N]
    unsigned short* __restrict__ C,         // [M,N] bf16 bits
    int M, int N, int K, int permute) {
  __shared__ unsigned short As[BM * PSTR];
  __shared__ unsigned short Bs[BM * PSTR];
  const int tid = threadIdx.x;
  const int nbn = N / BN;
  const int m0 = (blockIdx.x / nbn) * BM;
  const int n0 = (blockIdx.x % nbn) * BN;
  const int w = tid >> 6;
  const int l = tid & 63;
  const int ln = l & 15;
  const int k8 = l >> 4;
  const int wr = (w >> 1) * 64;
  const int wc = (w & 1) * 64;
  const int row_a = tid >> 2;
  const int c8 = (tid & 3) * 8;

  f32x4 acc[4][4];
#pragma unroll
  for (int a = 0; a < 4; a++)
#pragma unroll
    for (int b = 0; b < 4; b++) acc[a][b] = f32x4{0.f, 0.f, 0.f, 0.f};

  for (int k0 = 0; k0 < K; k0 += BK) {
    uint4 a0 = *(const uint4*)(A + (size_t)(m0 + row_a) * K + k0 + c8);
    uint4 a1 = *(const uint4*)(A + (size_t)(m0 + row_a + 64) * K + k0 + c8);
    uint4 b0 = *(const uint4*)(Bt + (size_t)(n0 + row_a) * K + k0 + c8);
    uint4 b1 = *(const uint4*)(Bt + (size_t)(n0 + row_a + 64) * K + k0 + c8);
    __syncthreads();
    *(uint4*)(As + row_a * PSTR + c8) = a0;
    *(uint4*)(As + (row_a + 64) * PSTR + c8) = a1;
    *(uint4*)(Bs + row_a * PSTR + c8) = b0;
    *(uint4*)(Bs + (row_a + 64) * PSTR + c8) = b1;
    __syncthreads();
    bf16x8 af[4], bfr[4];
#pragma unroll
    for (int mi = 0; mi < 4; mi++)
      af[mi] = *(const bf16x8*)(As + (wr + mi * 16 + ln) * PSTR + k8 * 8);
#pragma unroll
    for (int ni = 0; ni < 4; ni++)
      bfr[ni] = *(const bf16x8*)(Bs + (wc + ni * 16 + ln) * PSTR + k8 * 8);
#pragma unroll
    for (int mi = 0; mi < 4; mi++)
#pragma unroll
      for (int ni = 0; ni < 4; ni++)
        acc[mi][ni] = __builtin_amdgcn_mfma_f32_16x16x32_bf16(
            af[mi], bfr[ni], acc[mi][ni], 0, 0, 0);
  }
#pragma unroll
  for (int ni = 0; ni < 4; ni++) {
    int n = n0 + wc + ni * 16 + ln;
    float bv = bias[n];
#pragma unroll
    for (int mi = 0; mi < 4; mi++) {
#pragma unroll
      for (int r = 0; r < 4; r++) {
        int m = m0 + wr + mi * 16 + k8 * 4 + r;
        size_t ci;
        if (permute) {
          unsigned j = (unsigned)n & 1023u;
          ci = (size_t)m * N +
               (size_t)((j >> 4) * 80u + (((unsigned)n >> 10) << 4) + (j & 15u));
        } else {
          ci = (size_t)m * N + n;
        }
        C[ci] = f2bfbits(acc[mi][ni][r] + bv);
      }
    }
  }
}

// ---------------- persistent scan: 64 blocks, 16 dims each ----------------
// Role-specialized waves (10 waves / 640 threads):
//   wave 0: poll h(t-1) + stage packed h to LDS
//   wave 1: gxp prefetch, DEPTH-2 pipeline (full-iteration flight)
//   waves 8,9: replicated gates + state; wave 9 publishes (sc1), wave 8 -> out
//   all waves: matvec row tid>>3 (80 rows x 8 lanes), W in 16 x u32x4 regs
// Tagged words: (tag=t+1)<<16 | bf16(h). Tags 1..8192 never match zero-fill or
// 0xAAAA poison; stale same-tag words from a prior replay carry identical data
// (deterministic recurrence), so no reset is needed.
__global__ __launch_bounds__(THREADS, 1) void scan_kernel(
    const float* __restrict__ times,
    const float* __restrict__ Ui, const float* __restrict__ Uf2,
    const float* __restrict__ Uo, const float* __restrict__ Uz,
    const float* __restrict__ Ud,
    const unsigned short* __restrict__ gxp,  // [NSTEPS][64][80] bf16 bits
    unsigned int* __restrict__ hbuf,         // [2][DH] tagged words
    float* __restrict__ out) {
  __shared__ unsigned int hpk[DH / 2];      // packed bf16 pairs of h
  __shared__ float s_lds[WROWS];
  __shared__ float gx_ring[2][WROWS];
  __shared__ float t_lds[NSTEPS];           // 32 KB: event times

  const int tid = threadIdx.x;
  const int wid = tid >> 6;
  const int l = tid & 63;
  const int bid = blockIdx.x;
  const int j0 = bid * DPB;
  const int row = tid >> 3;  // 0..79
  const int ln8 = tid & 7;

  // ---- init: W slice into registers (16 x u32x4 = 64 VGPR equiv) ----
  u32x4 Wreg[16];
  {
    const float* Us[5] = {Ui, Uf2, Uo, Uz, Ud};
    const float* wsrc = Us[row >> 4] + (size_t)(j0 + (row & 15)) * DH + ln8 * 8;
#pragma unroll
    for (int i = 0; i < 16; i++) {
      float4 a = *(const float4*)(wsrc + i * 64);
      float4 b = *(const float4*)(wsrc + i * 64 + 4);
      Wreg[i] = u32x4{pk2(a.x, a.y), pk2(a.z, a.w), pk2(b.x, b.y), pk2(b.z, b.w)};
    }
  }
  // times -> LDS
  for (int k = tid; k < NSTEPS / 4; k += THREADS)
    ((float4*)t_lds)[k] = ((const float4*)times)[k];
  // h(=0) staging
  for (int k = tid; k < DH / 2; k += THREADS) hpk[k] = 0u;
  // gx pipeline init: ring[0] = gx(0) direct; gB holds in-flight gx(1)
  ushort4 gA = {0, 0, 0, 0}, gB = {0, 0, 0, 0};
  if (wid == 1 && l < 20) {
    ushort4 g0 = *(const ushort4*)(gxp + (size_t)0 * G5 + bid * WROWS + l * 4);
    gx_ring[0][l * 4 + 0] = bfbits2f((unsigned int)g0.x);
    gx_ring[0][l * 4 + 1] = bfbits2f((unsigned int)g0.y);
    gx_ring[0][l * 4 + 2] = bfbits2f((unsigned int)g0.z);
    gx_ring[0][l * 4 + 3] = bfbits2f((unsigned int)g0.w);
    gB = *(const ushort4*)(gxp + (size_t)1 * G5 + bid * WROWS + l * 4);
  }
  float cbv = 0.f, cd_reg = 0.f;  // replicated state (waves 8,9; lanes l<16)
  __syncthreads();

  // one scan step; gUse = gx value for step t+1 (issued a full iter ago),
  // gIss receives the load for step t+2.
  auto step = [&](int t, ushort4& gUse, ushort4& gIss) {
    // ---- hoisted, latency-tolerant reads (all stable since iter t-1) ----
    float gxv0 = 0.f, gxv1 = 0.f, gxv2 = 0.f, gxv3 = 0.f, gxv4 = 0.f;
    float tc = 0.f, tn = 0.f;
    if (wid >= 8 && l < DPB) {
      const float* gx = gx_ring[t & 1];
      gxv0 = gx[l];
      gxv1 = gx[16 + l];
      gxv2 = gx[32 + l];
      gxv3 = gx[48 + l];
      gxv4 = gx[64 + l];
      tc = t_lds[t];
      tn = t_lds[t + (t < NSTEPS - 1 ? 1 : 0)];
    }
    if (wid == 1 && l < 20) {  // issue gx load for step t+2 (depth-2)
      int tf = t + 2 < NSTEPS ? t + 2 : NSTEPS - 1;
      gIss = *(const ushort4*)(gxp + (size_t)tf * G5 + bid * WROWS + l * 4);
    }

    if (wid == 0 && t > 0) {  // wave 0: poll h(t-1)
      const unsigned int want = (unsigned int)t;  // tag = (t-1)+1
      const u32x4* pb = (const u32x4*)(hbuf + ((t - 1) & 1) * DH) + l;
      u32x4 A, B, C2, D2;
      for (;;) {
        asm volatile(
            "global_load_dwordx4 %0, %4, off sc1\n\t"
            "global_load_dwordx4 %1, %4, off offset:1024 sc1\n\t"
            "global_load_dwordx4 %2, %4, off offset:2048 sc1\n\t"
            "global_load_dwordx4 %3, %4, off offset:3072 sc1\n\t"
            "s_waitcnt vmcnt(0)"
            : "=&v"(A), "=&v"(B), "=&v"(C2), "=&v"(D2)
            : "v"(pb)
            : "memory");
        bool ok = (A[0] >> 16) == want && (A[1] >> 16) == want &&
                  (A[2] >> 16) == want && (A[3] >> 16) == want &&
                  (B[0] >> 16) == want && (B[1] >> 16) == want &&
                  (B[2] >> 16) == want && (B[3] >> 16) == want &&
                  (C2[0] >> 16) == want && (C2[1] >> 16) == want &&
                  (C2[2] >> 16) == want && (C2[3] >> 16) == want &&
                  (D2[0] >> 16) == want && (D2[1] >> 16) == want &&
                  (D2[2] >> 16) == want && (D2[3] >> 16) == want;
        if (__all(ok)) break;
      }
      *(u32x2*)(hpk + 2 * l) =
          u32x2{(A[0] & 0xffffu) | (A[1] << 16), (A[2] & 0xffffu) | (A[3] << 16)};
      *(u32x2*)(hpk + 128 + 2 * l) =
          u32x2{(B[0] & 0xffffu) | (B[1] << 16), (B[2] & 0xffffu) | (B[3] << 16)};
      *(u32x2*)(hpk + 256 + 2 * l) = u32x2{(C2[0] & 0xffffu) | (C2[1] << 16),
                                           (C2[2] & 0xffffu) | (C2[3] << 16)};
      *(u32x2*)(hpk + 384 + 2 * l) = u32x2{(D2[0] & 0xffffu) | (D2[1] << 16),
                                           (D2[2] & 0xffffu) | (D2[3] << 16)};
    }
    __syncthreads();  // b1: h staged (zeros at t==0)

    // ---- matvec: 80 rows x 1024, 8 lanes/row, W in regs ----
    {
#if HAVE_DOT2
      float a0 = 0.f, a1 = 0.f, a2 = 0.f, a3 = 0.f;
#pragma unroll
      for (int i = 0; i < 16; i++) {
        u32x4 hv = *(const u32x4*)(hpk + i * 32 + ln8 * 4);
        a0 = __builtin_amdgcn_fdot2_f32_bf16(asp(Wreg[i][0]), asp(hv[0]), a0, false);
        a1 = __builtin_amdgcn_fdot2_f32_bf16(asp(Wreg[i][1]), asp(hv[1]), a1, false);
        a2 = __builtin_amdgcn_fdot2_f32_bf16(asp(Wreg[i][2]), asp(hv[2]), a2, false);
        a3 = __builtin_amdgcn_fdot2_f32_bf16(asp(Wreg[i][3]), asp(hv[3]), a3, false);
      }
      float s = (a0 + a1) + (a2 + a3);
#else
      float a0 = 0.f, a1 = 0.f;
#pragma unroll
      for (int i = 0; i < 16; i++) {
        u32x4 hv = *(const u32x4*)(hpk + i * 32 + ln8 * 4);
        a0 += bfbits2f(Wreg[i][0] & 0xffffu) * bfbits2f(hv[0] & 0xffffu);
        a1 += bfhi2f(Wreg[i][0]) * bfhi2f(hv[0]);
        a0 += bfbits2f(Wreg[i][1] & 0xffffu) * bfbits2f(hv[1] & 0xffffu);
        a1 += bfhi2f(Wreg[i][1]) * bfhi2f(hv[1]);
        a0 += bfbits2f(Wreg[i][2] & 0xffffu) * bfbits2f(hv[2] & 0xffffu);
        a1 += bfhi2f(Wreg[i][2]) * bfhi2f(hv[2]);
        a0 += bfbits2f(Wreg[i][3] & 0xffffu) * bfbits2f(hv[3] & 0xffffu);
        a1 += bfhi2f(Wreg[i][3]) * bfhi2f(hv[3]);
      }
      float s = a0 + a1;
#endif
      s += __shfl_xor(s, 1);
      s += __shfl_xor(s, 2);
      s += __shfl_xor(s, 4);
      if (ln8 == 0) s_lds[row] = s;
    }
    if (wid == 1 && l < 20) {  // write gx(t+1) into ring (full-iter flight)
      gx_ring[(t + 1) & 1][l * 4 + 0] = bfbits2f((unsigned int)gUse.x);
      gx_ring[(t + 1) & 1][l * 4 + 1] = bfbits2f((unsigned int)gUse.y);
      gx_ring[(t + 1) & 1][l * 4 + 2] = bfbits2f((unsigned int)gUse.z);
      gx_ring[(t + 1) & 1][l * 4 + 3] = bfbits2f((unsigned int)gUse.w);
    }
    __syncthreads();  // b2: s_lds + ring ready

    if (wid >= 8) {  // waves 8,9: replicated gates + state
      unsigned int word = 0;
      float h = 0.f, cn = 0.f, adv = 0.f, ig = 0.f, fg = 0.f, z = 0.f;
      if (l < DPB) {
        float si = s_lds[l] + gxv0;
        float sf = s_lds[16 + l] + gxv1;
        float so = s_lds[32 + l] + gxv2;
        float sz = s_lds[48 + l] + gxv3;
        float sd = s_lds[64 + l] + gxv4;
        ig = 1.f / (1.f + __expf(-si));
        fg = 1.f / (1.f + __expf(-sf));
        float og = 1.f / (1.f + __expf(-so));
        z = 1.f - 2.f / (__expf(2.f * sz) + 1.f);
        cn = fg * cd_reg + ig * z;
        float th = 1.f - 2.f / (__expf(2.f * cn) + 1.f);
        h = og * th;
        adv = sd;
        word = (((unsigned int)(t + 1) & 0xffffu) << 16) |
               (unsigned int)f2bfbits(h);
      }
      if (wid == 9) {  // publish ASAP (16 words = 64 B, lanes 0-3)
        u32x4 pubv = {__shfl(word, 4 * l + 0), __shfl(word, 4 * l + 1),
                      __shfl(word, 4 * l + 2), __shfl(word, 4 * l + 3)};
        if (l < 4) {
          u32x4* dst = (u32x4*)(hbuf + (t & 1) * DH + bid * DPB) + l;
          asm volatile("global_store_dwordx4 %0, %1, off sc1" ::"v"(dst),
                       "v"(pubv)
                       : "memory");
        }
      }
      if (l < DPB) {
        float dec = fmaxf(adv, 0.f) + __logf(1.f + __expf(-fabsf(adv)));
        cbv = fg * cbv + ig * z;
        cd_reg = cbv + (cn - cbv) * __expf(-dec * (tn - tc));
        if (wid == 8) {
          int j = j0 + l;
          out[(size_t)t * DH + j] = h;
          out[NHOUT + (size_t)t * DH + j] = cn;
          out[2 * NHOUT + (size_t)t * DH + j] = dec;
        }
      }
    }
    // waves 0-7 run ahead; wave 0 starts polling h(t) immediately.
  };

  for (int t = 0; t < NSTEPS; t += 2) {
    step(t, gB, gA);      // uses gx(t+1) [in gB], issues gx(t+2) -> gA
    step(t + 1, gA, gB);  // uses gx(t+2) [in gA], issues gx(t+3) -> gB
  }
  if (wid == 8 && l < DPB) out[3 * NHOUT + j0 + l] = cbv;
}

extern "C" void kernel_launch(void* const* d_in, const int* in_sizes, int n_in,
                              void* d_out, int out_size, void* d_ws,
                              size_t ws_size, hipStream_t stream) {
  (void)in_sizes; (void)n_in; (void)out_size; (void)ws_size;
  const float* times = (const float*)d_in[0];
  const float* marks = (const float*)d_in[1];
  const float* Wp = (const float*)d_in[3];
  const float* bp = (const float*)d_in[4];
  const float* Wi = (const float*)d_in[5];
  const float* bi = (const float*)d_in[6];
  const float* Wf = (const float*)d_in[7];
  const float* bf_ = (const float*)d_in[8];
  const float* Wo = (const float*)d_in[9];
  const float* bo = (const float*)d_in[10];
  const float* Wz = (const float*)d_in[11];
  const float* bz = (const float*)d_in[12];
  const float* Wd = (const float*)d_in[13];
  const float* bd = (const float*)d_in[14];
  const float* Ui = (const float*)d_in[15];
  const float* Uf2 = (const float*)d_in[16];
  const float* Uo = (const float*)d_in[17];
  const float* Uz = (const float*)d_in[18];
  const float* Ud = (const float*)d_in[19];

  char* ws = (char*)d_ws;
  size_t off = 0;
  auto alloc = [&](size_t bytes) -> void* {
    void* p = ws + off;
    off += (bytes + 255) & ~(size_t)255;
    return p;
  };
  unsigned short* marks_bf = (unsigned short*)alloc((size_t)NSTEPS * DIN * 2);
  unsigned short* X_bf = (unsigned short*)alloc((size_t)NSTEPS * DH * 2);
  unsigned short* Wp_bf = (unsigned short*)alloc((size_t)DH * DIN * 2);
  unsigned short* W5_bf = (unsigned short*)alloc((size_t)G5 * DH * 2);
  float* bcat = (float*)alloc((size_t)G5 * 4);
  unsigned short* gxp = (unsigned short*)alloc((size_t)NSTEPS * G5 * 2);
  unsigned int* hbuf = (unsigned int*)alloc((size_t)2 * DH * 4);

  auto cvt = [&](const float* s, unsigned short* d, int n) {
    int n4 = n / 4;
    int grid = (n4 + 255) / 256;
    if (grid > 2048) grid = 2048;
    cvt_f32_bf16<<<grid, 256, 0, stream>>>(s, d, n4);
  };
  cvt(marks, marks_bf, NSTEPS * DIN);
  cvt(Wp, Wp_bf, DH * DIN);
  cvt(Wi, W5_bf + (size_t)0 * DH * DH, DH * DH);
  cvt(Wf, W5_bf + (size_t)1 * DH * DH, DH * DH);
  cvt(Wo, W5_bf + (size_t)2 * DH * DH, DH * DH);
  cvt(Wz, W5_bf + (size_t)3 * DH * DH, DH * DH);
  cvt(Wd, W5_bf + (size_t)4 * DH * DH, DH * DH);
  hipMemcpyAsync(bcat + 0 * DH, bi, DH * sizeof(float),
                 hipMemcpyDeviceToDevice, stream);
  hipMemcpyAsync(bcat + 1 * DH, bf_, DH * sizeof(float),
                 hipMemcpyDeviceToDevice, stream);
  hipMemcpyAsync(bcat + 2 * DH, bo, DH * sizeof(float),
                 hipMemcpyDeviceToDevice, stream);
  hipMemcpyAsync(bcat + 3 * DH, bz, DH * sizeof(float),
                 hipMemcpyDeviceToDevice, stream);
  hipMemcpyAsync(bcat + 4 * DH, bd, DH * sizeof(float),
                 hipMemcpyDeviceToDevice, stream);

  // X = marks @ Wp.T + bp   [8192,1024]
  gemm_bt<<<(NSTEPS / BM) * (DH / BN), 256, 0, stream>>>(
      marks_bf, Wp_bf, bp, X_bf, NSTEPS, DH, DIN, 0);
  // gxp = permute(X @ [Wi;Wf;Wo;Wz;Wd].T + bcat)   [8192][64][5][16]
  gemm_bt<<<(NSTEPS / BM) * (G5 / BN), 256, 0, stream>>>(
      X_bf, W5_bf, bcat, gxp, NSTEPS, G5, DH, 1);

  scan_kernel<<<NBLK, THREADS, 0, stream>>>(times, Ui, Uf2, Uo, Uz, Ud, gxp,
                                            hbuf, (float*)d_out);
}